// Round 7
// baseline (54.592 us; speedup 1.0000x reference)
//
#include <hip/hip_runtime.h>

#define NG 2
#define NV 320
#define GV 640      // NG*NV
#define DHALF 128   // CODE_DIM/NG
#define BSROWS 2048 // B*S
#define NROWS 4096  // BSROWS*NG
#define K_DIM 512
#define NPART 1024  // row-kernel blocks (partials)
#define NRED 40     // reduce blocks (16 cols each)
#define LDA 40      // f16 per LDS row (32 + 8 pad); 80 B, 16B-aligned

typedef _Float16 half8 __attribute__((ext_vector_type(8)));
typedef _Float16 half4 __attribute__((ext_vector_type(4)));
typedef float floatx4 __attribute__((ext_vector_type(4)));

#define MFMA16(a, b, c) __builtin_amdgcn_mfma_f32_16x16x32_f16(a, b, c, 0, 0, 0)

// ---------------- Prep: split W (transposed) and X into f16 hi/lo; zero counter ------------
// blocks 0..319: W[512][640] -> Wth/Wtl [640][512] (scale 1024)
// blocks 320..831: X[2048*512] -> Xh/Xl (scale 64), straight layout
__global__ __launch_bounds__(256) void prep_kernel(
    const float* __restrict__ W, const float* __restrict__ X,
    _Float16* __restrict__ Wth, _Float16* __restrict__ Wtl,
    _Float16* __restrict__ Xh, _Float16* __restrict__ Xl,
    int* __restrict__ counter) {
  const int t = threadIdx.x;
  const int bid = blockIdx.x;
  if (bid == 0 && t == 0) *counter = 0;
  if (bid < 320) {
    __shared__ float T[32][33];
    const int n0 = (bid % 20) * 32, k0 = (bid / 20) * 32;
    const int r = t >> 3, c4 = (t & 7) << 2;
    float4 v = *(const float4*)(W + (k0 + r) * GV + n0 + c4);
    T[r][c4 + 0] = v.x; T[r][c4 + 1] = v.y; T[r][c4 + 2] = v.z; T[r][c4 + 3] = v.w;
    __syncthreads();
    const int nr = t >> 3, k4 = (t & 7) << 2;
    half4 hv, lv;
#pragma unroll
    for (int j = 0; j < 4; ++j) {
      float s = T[k4 + j][nr] * 1024.0f;
      _Float16 h = (_Float16)s;
      hv[j] = h;
      lv[j] = (_Float16)(s - (float)h);
    }
    *(half4*)(Wth + (n0 + nr) * K_DIM + k0 + k4) = hv;
    *(half4*)(Wtl + (n0 + nr) * K_DIM + k0 + k4) = lv;
  } else {
    const int off = (bid - 320) * 2048 + t * 8;  // covers 2048*512 = 512 blocks * 2048
    float4 a = *(const float4*)(X + off);
    float4 b = *(const float4*)(X + off + 4);
    float xv[8] = {a.x, a.y, a.z, a.w, b.x, b.y, b.z, b.w};
    half8 hv, lv;
#pragma unroll
    for (int j = 0; j < 8; ++j) {
      float s = xv[j] * 64.0f;
      _Float16 h = (_Float16)s;
      hv[j] = h;
      lv[j] = (_Float16)(s - (float)h);
    }
    *(half8*)(Xh + off) = hv;
    *(half8*)(Xl + off) = lv;
  }
}

// ---------------- GEMM: logits = x@W + b; BM=64 BN=32 BK=32; pure-f16 staging --------------
__global__ __launch_bounds__(256) void gemm_mfma_kernel(
    const _Float16* __restrict__ Xh, const _Float16* __restrict__ Xl,
    const _Float16* __restrict__ Wth, const _Float16* __restrict__ Wtl,
    const float* __restrict__ bias, float* __restrict__ C) {
  __shared__ _Float16 Ah[2][64 * LDA], Al[2][64 * LDA];
  __shared__ _Float16 Bh[2][32 * LDA], Bl[2][32 * LDA];
  const int tid = threadIdx.x;
  const int bm = blockIdx.y * 64, bn = blockIdx.x * 32;
  const int w = tid >> 6, lane = tid & 63;
  const int wr = w >> 1, wc = w & 1;

  // A staging: 64 rows x 32 k = 2048 halves x2; 256 thr x half8 each
  const int srow = tid >> 2;
  const int skc = (tid & 3) << 3;
  const _Float16* Ahg = Xh + (bm + srow) * K_DIM + skc;
  const _Float16* Alg = Xl + (bm + srow) * K_DIM + skc;
  const int sA = srow * LDA + skc;
  // B staging: 32 rows x 32 k; threads 0..127 x half8
  const int brow = tid >> 2;  // valid when tid < 128
  const int bkc = (tid & 3) << 3;
  const _Float16* Bhg = Wth + (bn + brow) * K_DIM + bkc;
  const _Float16* Blg = Wtl + (bn + brow) * K_DIM + bkc;
  const int sB = brow * LDA + bkc;

  const int frow = lane & 15;
  const int fkg = (lane >> 4) << 3;
  const int a0o = (wr * 32 + frow) * LDA + fkg;
  const int b0o = (wc * 16 + frow) * LDA + fkg;

  floatx4 acc[2] = {};

  // prologue: stage tile 0
  {
    half8 ahv = *(const half8*)(Ahg);
    half8 alv = *(const half8*)(Alg);
    *(half8*)&Ah[0][sA] = ahv;
    *(half8*)&Al[0][sA] = alv;
    if (tid < 128) {
      half8 bhv = *(const half8*)(Bhg);
      half8 blv = *(const half8*)(Blg);
      *(half8*)&Bh[0][sB] = bhv;
      *(half8*)&Bl[0][sB] = blv;
    }
  }
  __syncthreads();

#pragma unroll 2
  for (int k0 = 0; k0 < K_DIM; k0 += 32) {
    const int cur = (k0 >> 5) & 1;
    const int nxt = cur ^ 1;
    const bool more = (k0 + 32) < K_DIM;

    half8 ahv, alv, bhv, blv;
    if (more) {
      ahv = *(const half8*)(Ahg + k0 + 32);
      alv = *(const half8*)(Alg + k0 + 32);
      if (tid < 128) {
        bhv = *(const half8*)(Bhg + k0 + 32);
        blv = *(const half8*)(Blg + k0 + 32);
      }
    }

    half8 ah0 = *(const half8*)&Ah[cur][a0o];
    half8 ah1 = *(const half8*)&Ah[cur][a0o + 16 * LDA];
    half8 al0 = *(const half8*)&Al[cur][a0o];
    half8 al1 = *(const half8*)&Al[cur][a0o + 16 * LDA];
    half8 bh0 = *(const half8*)&Bh[cur][b0o];
    half8 bl0 = *(const half8*)&Bl[cur][b0o];

    // per-output order: hh, hl, lh (bit-identical to prior rounds)
    acc[0] = MFMA16(ah0, bh0, acc[0]);
    acc[1] = MFMA16(ah1, bh0, acc[1]);
    acc[0] = MFMA16(ah0, bl0, acc[0]);
    acc[1] = MFMA16(ah1, bl0, acc[1]);
    acc[0] = MFMA16(al0, bh0, acc[0]);
    acc[1] = MFMA16(al1, bh0, acc[1]);

    if (more) {
      *(half8*)&Ah[nxt][sA] = ahv;
      *(half8*)&Al[nxt][sA] = alv;
      if (tid < 128) {
        *(half8*)&Bh[nxt][sB] = bhv;
        *(half8*)&Bl[nxt][sB] = blv;
      }
    }
    __syncthreads();
  }

  // C/D: col = lane&15, row = (lane>>4)*4 + reg
  const float inv = 1.0f / 65536.0f;
  const int col = bn + wc * 16 + (lane & 15);
  const float bb = bias[col];
#pragma unroll
  for (int i = 0; i < 2; ++i) {
    const int r0 = bm + wr * 32 + i * 16 + ((lane >> 4) << 2);
#pragma unroll
    for (int q = 0; q < 4; ++q)
      C[(r0 + q) * GV + col] = acc[i][q] * inv + bb;
  }
}

// ---------------- Row kernel: 1 row/wave; fused gather; per-block partials -----------------
__global__ __launch_bounds__(256) void row_kernel(
    const float* __restrict__ logits, const float* __restrict__ gumbels,
    const float* __restrict__ cvs, float* __restrict__ out,
    float* __restrict__ part) {
  __shared__ float accW[4][NV];
  const int tid = threadIdx.x;
  const int lane = tid & 63;
  const int w = tid >> 6;
  const int r = blockIdx.x * 4 + w;  // row in [0,4096)
  const int bs = r >> 1, g = r & 1;
  const float* lrow = logits + bs * GV + g * NV;
  const float* grow = gumbels + r * NV;

  float lv[5], av[5];
#pragma unroll
  for (int j = 0; j < 5; ++j) {
    lv[j] = lrow[lane + 64 * j];
    av[j] = lv[j] + grow[lane + 64 * j];
  }
  float m = lv[0];
#pragma unroll
  for (int j = 1; j < 5; ++j) m = fmaxf(m, lv[j]);
#pragma unroll
  for (int o = 32; o > 0; o >>= 1) m = fmaxf(m, __shfl_xor(m, o));
  float e[5];
  float s = 0.f;
#pragma unroll
  for (int j = 0; j < 5; ++j) {
    e[j] = expf(lv[j] - m);
    s += e[j];
  }
#pragma unroll
  for (int o = 32; o > 0; o >>= 1) s += __shfl_xor(s, o);
  const float inv = 1.f / s;
#pragma unroll
  for (int j = 0; j < 5; ++j) accW[w][lane + 64 * j] = e[j] * inv;

  float bv = av[0];
  int bi = lane;
#pragma unroll
  for (int j = 1; j < 5; ++j) {
    if (av[j] > bv) { bv = av[j]; bi = lane + 64 * j; }
  }
#pragma unroll
  for (int o = 32; o > 0; o >>= 1) {
    float ov = __shfl_xor(bv, o);
    int oi = __shfl_xor(bi, o);
    if (ov > bv || (ov == bv && oi < bi)) { bv = ov; bi = oi; }
  }

  const float2 cv = *(const float2*)(cvs + (g * NV + bi) * DHALF + lane * 2);
  *(float2*)(out + bs * 256 + g * DHALF + lane * 2) = cv;

  __syncthreads();
  for (int i = tid; i < GV; i += 256) {
    float v = (i < NV) ? (accW[0][i] + accW[2][i]) : (accW[1][i - NV] + accW[3][i - NV]);
    part[blockIdx.x * GV + i] = v;
  }
}

// ---------------- Reduce partials + perplexity: 40 blocks x 16 cols ------------------------
__global__ __launch_bounds__(256) void reduce_perp_kernel(
    const float* __restrict__ part, float* __restrict__ hpart,
    int* __restrict__ counter, float* __restrict__ perpOut) {
  const int t = threadIdx.x;
  const int rg = t >> 4;        // 0..15 row-group
  const int co = t & 15;        // 0..15 col offset
  const int col = blockIdx.x * 16 + co;
  float s = 0.f;
  for (int b = rg; b < NPART; b += 16) s += part[b * GV + col];
  __shared__ float red[16][16];
  red[rg][co] = s;
  __syncthreads();
  if (t < 16) {
    float cs = 0.f;
#pragma unroll
    for (int j = 0; j < 16; ++j) cs += red[j][t];
    const float mm = cs * (1.0f / BSROWS);
    float h = mm * logf(mm + 1e-7f);
#pragma unroll
    for (int o = 8; o > 0; o >>= 1) h += __shfl_xor(h, o, 16);
    if (t == 0) {
      hpart[blockIdx.x] = h;
      __threadfence();
      const int old = atomicAdd(counter, 1);
      if (old == NRED - 1) {
        __threadfence();
        float h0 = 0.f, h1 = 0.f;
#pragma unroll
        for (int i = 0; i < 20; ++i) h0 += hpart[i];
#pragma unroll
        for (int i = 20; i < 40; ++i) h1 += hpart[i];
        perpOut[0] = expf(-h0) + expf(-h1);
      }
    }
  }
}

extern "C" void kernel_launch(void* const* d_in, const int* in_sizes, int n_in,
                              void* d_out, int out_size, void* d_ws, size_t ws_size,
                              hipStream_t stream) {
  const float* x = (const float*)d_in[0];
  const float* W = (const float*)d_in[1];
  const float* b = (const float*)d_in[2];
  const float* cvs = (const float*)d_in[3];
  const float* gum = (const float*)d_in[4];
  float* out = (float*)d_out;

  float* logits = (float*)d_ws;                     // 2048*640 f32
  float* part = logits + BSROWS * GV;               // 1024*640 f32
  float* hpart = part + NPART * GV;                 // 40 f32 (+pad)
  int* counter = (int*)(hpart + 64);                // 1 i32 (+pad)
  _Float16* Wth = (_Float16*)(counter + 4);         // 640*512 f16
  _Float16* Wtl = Wth + GV * K_DIM;                 // 640*512 f16
  _Float16* Xh = Wtl + GV * K_DIM;                  // 2048*512 f16
  _Float16* Xl = Xh + BSROWS * K_DIM;               // 2048*512 f16

  prep_kernel<<<832, 256, 0, stream>>>(W, x, Wth, Wtl, Xh, Xl, counter);
  dim3 ggrid(GV / 32, BSROWS / 64);  // (20, 32) = 640 blocks
  gemm_mfma_kernel<<<ggrid, 256, 0, stream>>>(Xh, Xl, Wth, Wtl, b, logits);
  row_kernel<<<NROWS / 4, 256, 0, stream>>>(logits, gum, cvs, out, part);
  reduce_perp_kernel<<<NRED, 256, 0, stream>>>(part, hpart, counter, out + BSROWS * 256);
}